// Round 2
// baseline (12954.373 us; speedup 1.0000x reference)
//
#include <hip/hip_runtime.h>

#define T_LEN 8192
#define N_NODES 33
#define N_EDGES 64
#define DIM_IN 3
#define D_H 64
#define D_LSTM 128
#define N_CLS 5
#define TB 4   // timesteps per block in kernel 1

// ---------------------------------------------------------------------------
// Kernel 1: graph conv x2 + relu + mean over nodes + input-side LSTM projection
// Writes A[t][o] = seq_t @ W_ih.T + b_ih + b_hh   (T x 512)
// One block = 64 threads (1 wave) handles TB consecutive timesteps.
// ---------------------------------------------------------------------------
__global__ __launch_bounds__(64, 2) void gnn_proj_kernel(
    const float* __restrict__ x,        // (T,33,3)
    const int*   __restrict__ esrc,     // (64,)
    const int*   __restrict__ edst,     // (64,)
    const float* __restrict__ W_rel1,   // (64,3)
    const float* __restrict__ b_rel1,   // (64,)
    const float* __restrict__ W_root1,  // (64,3)
    const float* __restrict__ W_rel2,   // (64,64)
    const float* __restrict__ b_rel2,   // (64,)
    const float* __restrict__ W_root2,  // (64,64)
    const float* __restrict__ W_ih,     // (512,64)
    const float* __restrict__ b_ih,     // (512,)
    const float* __restrict__ b_hh,     // (512,)
    float* __restrict__ A)              // (T,512)  [workspace]
{
    const int t0 = blockIdx.x * TB;
    const int j  = threadIdx.x;   // 0..63, owns feature dim j

    __shared__ __align__(16) float x_s[N_NODES][DIM_IN];
    __shared__ __align__(16) float agg1[N_NODES][DIM_IN];
    __shared__ __align__(16) float h1[N_NODES][D_H];
    __shared__ __align__(16) float agg2[N_NODES][D_H];
    __shared__ __align__(16) float seq_s[TB][D_H];
    __shared__ int es[N_EDGES], ed[N_EDGES];

    es[j] = esrc[j];
    ed[j] = edst[j];

    // per-thread weights for layer 1 (row j)
    const float wr1_0 = W_rel1[j*3+0], wr1_1 = W_rel1[j*3+1], wr1_2 = W_rel1[j*3+2];
    const float wt1_0 = W_root1[j*3+0], wt1_1 = W_root1[j*3+1], wt1_2 = W_root1[j*3+2];
    const float br1 = b_rel1[j];
    const float br2 = b_rel2[j];

    // per-thread weights for layer 2 (row j) held in VGPRs
    float wr2[D_H], wt2[D_H];
    #pragma unroll
    for (int k = 0; k < D_H; ++k) {
        wr2[k] = W_rel2[j*D_H + k];
        wt2[k] = W_root2[j*D_H + k];
    }

    for (int tt = 0; tt < TB; ++tt) {
        const int t = t0 + tt;
        __syncthreads();   // protect LDS from previous iteration's readers

        // ---- load x_t (99 floats) ----
        const float* xt = x + (size_t)t * (N_NODES * DIM_IN);
        for (int i = j; i < N_NODES * DIM_IN; i += 64) x_s[0][i] = xt[i];
        __syncthreads();

        // ---- conv1 scatter-aggregate (per destination node, no atomics) ----
        if (j < N_NODES) {
            float a0 = 0.f, a1 = 0.f, a2 = 0.f;
            for (int e = 0; e < N_EDGES; ++e) {
                if (ed[e] == j) {
                    a0 += x_s[es[e]][0];
                    a1 += x_s[es[e]][1];
                    a2 += x_s[es[e]][2];
                }
            }
            agg1[j][0] = a0; agg1[j][1] = a1; agg1[j][2] = a2;
        }
        __syncthreads();

        // ---- h1[n][j] = agg1[n]·W_rel1[j] + b_rel1[j] + x[n]·W_root1[j]; zero agg2 ----
        for (int n = 0; n < N_NODES; ++n) {
            float v = br1
                + agg1[n][0]*wr1_0 + agg1[n][1]*wr1_1 + agg1[n][2]*wr1_2
                + x_s[n][0]*wt1_0  + x_s[n][1]*wt1_1  + x_s[n][2]*wt1_2;
            h1[n][j]  = v;
            agg2[n][j] = 0.f;
        }
        __syncthreads();

        // ---- conv2 scatter: thread j owns column j, fixed edge order ----
        for (int e = 0; e < N_EDGES; ++e) {
            agg2[ed[e]][j] += h1[es[e]][j];
        }
        __syncthreads();

        // ---- h2[n][j] -> relu -> mean over n ----
        float seqv = 0.f;
        for (int n = 0; n < N_NODES; ++n) {
            const float4* ag4 = (const float4*)agg2[n];
            const float4* h4  = (const float4*)h1[n];
            float acc0 = br2, acc1 = 0.f, acc2 = 0.f, acc3 = 0.f;
            #pragma unroll
            for (int k4 = 0; k4 < D_H/4; ++k4) {
                float4 av = ag4[k4];
                float4 hv = h4[k4];
                acc0 += av.x * wr2[4*k4+0] + hv.x * wt2[4*k4+0];
                acc1 += av.y * wr2[4*k4+1] + hv.y * wt2[4*k4+1];
                acc2 += av.z * wr2[4*k4+2] + hv.z * wt2[4*k4+2];
                acc3 += av.w * wr2[4*k4+3] + hv.w * wt2[4*k4+3];
            }
            float acc = (acc0 + acc1) + (acc2 + acc3);
            seqv += fmaxf(acc, 0.f);
        }
        seq_s[tt][j] = seqv * (1.0f / 33.0f);
    }
    __syncthreads();

    // ---- A[t][o] = b_ih[o]+b_hh[o] + seq_t · W_ih[o]  (8 outputs / thread) ----
    #pragma unroll
    for (int m = 0; m < 8; ++m) {
        const int o = m * 64 + j;
        const float bias = b_ih[o] + b_hh[o];
        const float4* w4 = (const float4*)(W_ih + (size_t)o * D_H);
        float acc[TB];
        #pragma unroll
        for (int tt = 0; tt < TB; ++tt) acc[tt] = bias;
        #pragma unroll
        for (int k4 = 0; k4 < D_H/4; ++k4) {
            float4 wv = w4[k4];
            #pragma unroll
            for (int tt = 0; tt < TB; ++tt) {
                const float4* s4 = (const float4*)seq_s[tt];
                float4 sv = s4[k4];
                acc[tt] += sv.x*wv.x + sv.y*wv.y + sv.z*wv.z + sv.w*wv.w;
            }
        }
        #pragma unroll
        for (int tt = 0; tt < TB; ++tt) {
            A[(size_t)(t0 + tt) * 512 + o] = acc[tt];
        }
    }
}

// ---------------------------------------------------------------------------
// Kernel 2: sequential LSTM, single block (1 CU), 256 threads = 4 waves.
// Thread j owns gate rows 2j and 2j+1 of W_hh: 64 float4 = 256 VGPRs resident
// (launch_bounds(256,1) -> 512-VGPR budget, 1 wave/SIMD).
// Per step: 32 broadcast ds_read_b128 of h serve BOTH gate rows (128 LDS
// reads/step CU-wide vs 256 before), 256 FMAs on 8 independent chains.
// ---------------------------------------------------------------------------
__device__ __forceinline__ float sigmoid_f(float v) {
    return 1.0f / (1.0f + __expf(-v));
}
__device__ __forceinline__ float tanh_f(float v) {
    // safe at both extremes: exp(2v)->inf => 1 ; ->0 => -1
    return 1.0f - 2.0f / (1.0f + __expf(2.0f * v));
}

__global__ __launch_bounds__(256, 1) void lstm_kernel(
    const float* __restrict__ A,      // (T,512)
    const float* __restrict__ W_hh,   // (512,128)
    const float* __restrict__ W_fc,   // (5,128)
    const float* __restrict__ b_fc,   // (5,)
    float* __restrict__ out)          // (5,)
{
    const int j  = threadIdx.x;   // 0..255
    const int r0 = 2 * j;         // this thread's two gate rows: r0, r0+1

    __shared__ __align__(16) float h_s[D_LSTM];
    __shared__ __align__(16) float gates_s[4 * D_LSTM];

    // W_hh rows r0, r0+1 in registers (64 float4 = 256 VGPRs)
    float4 wa[D_LSTM / 4], wb[D_LSTM / 4];
    {
        const float4* Wa4 = (const float4*)(W_hh + (size_t)r0 * D_LSTM);
        const float4* Wb4 = (const float4*)(W_hh + (size_t)(r0 + 1) * D_LSTM);
        #pragma unroll
        for (int k = 0; k < D_LSTM / 4; ++k) {
            wa[k] = Wa4[k];
            wb[k] = Wb4[k];
        }
    }

    float c = 0.f;
    if (j < D_LSTM) h_s[j] = 0.f;
    __syncthreads();

    float2 a_next = *(const float2*)(A + r0);  // prefetch t=0

    for (int t = 0; t < T_LEN; ++t) {
        float2 a = a_next;
        if (t + 1 < T_LEN)
            a_next = *(const float2*)(A + (size_t)(t + 1) * 512 + r0);

        // gates_pre[r0], gates_pre[r0+1] = a + h · w  (8 independent chains)
        const float4* h4 = (const float4*)h_s;
        float a0 = 0.f, a1 = 0.f, a2 = 0.f, a3 = 0.f;
        float b0 = 0.f, b1 = 0.f, b2 = 0.f, b3 = 0.f;
        #pragma unroll
        for (int k = 0; k < D_LSTM / 4; ++k) {
            float4 hv  = h4[k];       // broadcast LDS read, shared by both rows
            float4 wva = wa[k];
            float4 wvb = wb[k];
            a0 += hv.x * wva.x; a1 += hv.y * wva.y;
            a2 += hv.z * wva.z; a3 += hv.w * wva.w;
            b0 += hv.x * wvb.x; b1 += hv.y * wvb.y;
            b2 += hv.z * wvb.z; b3 += hv.w * wvb.w;
        }
        float2 g2;
        g2.x = a.x + ((a0 + a1) + (a2 + a3));
        g2.y = a.y + ((b0 + b1) + (b2 + b3));
        *(float2*)&gates_s[r0] = g2;   // one ds_write_b64
        __syncthreads();

        if (j < D_LSTM) {
            float gi = gates_s[j];
            float gf = gates_s[D_LSTM + j];
            float gg = gates_s[2 * D_LSTM + j];
            float go = gates_s[3 * D_LSTM + j];
            float si = sigmoid_f(gi);
            float sf = sigmoid_f(gf);
            float so = sigmoid_f(go);
            float tg = tanh_f(gg);
            c = sf * c + si * tg;
            h_s[j] = so * tanh_f(c);
        }
        __syncthreads();
    }

    // final FC: out = hT @ W_fc.T + b_fc
    if (j < N_CLS) {
        float acc = b_fc[j];
        #pragma unroll
        for (int k = 0; k < D_LSTM; ++k) acc += h_s[k] * W_fc[j * D_LSTM + k];
        out[j] = acc;
    }
}

// ---------------------------------------------------------------------------
extern "C" void kernel_launch(void* const* d_in, const int* in_sizes, int n_in,
                              void* d_out, int out_size, void* d_ws, size_t ws_size,
                              hipStream_t stream) {
    const float* x       = (const float*)d_in[0];
    const int*   esrc    = (const int*)  d_in[1];
    const int*   edst    = (const int*)  d_in[2];
    const float* W_rel1  = (const float*)d_in[3];
    const float* b_rel1  = (const float*)d_in[4];
    const float* W_root1 = (const float*)d_in[5];
    const float* W_rel2  = (const float*)d_in[6];
    const float* b_rel2  = (const float*)d_in[7];
    const float* W_root2 = (const float*)d_in[8];
    const float* W_ih    = (const float*)d_in[9];
    const float* W_hh    = (const float*)d_in[10];
    const float* b_ih    = (const float*)d_in[11];
    const float* b_hh    = (const float*)d_in[12];
    const float* W_fc    = (const float*)d_in[13];
    const float* b_fc    = (const float*)d_in[14];

    float* out = (float*)d_out;
    float* A   = (float*)d_ws;   // (T,512) f32 = 16 MB

    gnn_proj_kernel<<<T_LEN / TB, 64, 0, stream>>>(
        x, esrc, edst, W_rel1, b_rel1, W_root1,
        W_rel2, b_rel2, W_root2, W_ih, b_ih, b_hh, A);

    lstm_kernel<<<1, 256, 0, stream>>>(A, W_hh, W_fc, b_fc, out);
}

// Round 3
// 9325.813 us; speedup vs baseline: 1.3891x; 1.3891x over previous
//
#include <hip/hip_runtime.h>

#define T_LEN 8192
#define N_NODES 33
#define N_EDGES 64
#define DIM_IN 3
#define D_H 64
#define D_LSTM 128
#define N_CLS 5
#define TB 4   // timesteps per block in kernel 1

// ---------------------------------------------------------------------------
// Kernel 1: graph conv x2 + relu + mean over nodes + input-side LSTM projection
// Writes A[t][o] = seq_t @ W_ih.T + b_ih + b_hh   (T x 512)
// ---------------------------------------------------------------------------
__global__ __launch_bounds__(64, 2) void gnn_proj_kernel(
    const float* __restrict__ x,        // (T,33,3)
    const int*   __restrict__ esrc,     // (64,)
    const int*   __restrict__ edst,     // (64,)
    const float* __restrict__ W_rel1,   // (64,3)
    const float* __restrict__ b_rel1,   // (64,)
    const float* __restrict__ W_root1,  // (64,3)
    const float* __restrict__ W_rel2,   // (64,64)
    const float* __restrict__ b_rel2,   // (64,)
    const float* __restrict__ W_root2,  // (64,64)
    const float* __restrict__ W_ih,     // (512,64)
    const float* __restrict__ b_ih,     // (512,)
    const float* __restrict__ b_hh,     // (512,)
    float* __restrict__ A)              // (T,512)  [workspace]
{
    const int t0 = blockIdx.x * TB;
    const int j  = threadIdx.x;   // 0..63

    __shared__ __align__(16) float x_s[N_NODES][DIM_IN];
    __shared__ __align__(16) float agg1[N_NODES][DIM_IN];
    __shared__ __align__(16) float h1[N_NODES][D_H];
    __shared__ __align__(16) float agg2[N_NODES][D_H];
    __shared__ __align__(16) float seq_s[TB][D_H];
    __shared__ int es[N_EDGES], ed[N_EDGES];

    es[j] = esrc[j];
    ed[j] = edst[j];

    const float wr1_0 = W_rel1[j*3+0], wr1_1 = W_rel1[j*3+1], wr1_2 = W_rel1[j*3+2];
    const float wt1_0 = W_root1[j*3+0], wt1_1 = W_root1[j*3+1], wt1_2 = W_root1[j*3+2];
    const float br1 = b_rel1[j];
    const float br2 = b_rel2[j];

    float wr2[D_H], wt2[D_H];
    #pragma unroll
    for (int k = 0; k < D_H; ++k) {
        wr2[k] = W_rel2[j*D_H + k];
        wt2[k] = W_root2[j*D_H + k];
    }

    for (int tt = 0; tt < TB; ++tt) {
        const int t = t0 + tt;
        __syncthreads();

        const float* xt = x + (size_t)t * (N_NODES * DIM_IN);
        for (int i = j; i < N_NODES * DIM_IN; i += 64) x_s[0][i] = xt[i];
        __syncthreads();

        if (j < N_NODES) {
            float a0 = 0.f, a1 = 0.f, a2 = 0.f;
            for (int e = 0; e < N_EDGES; ++e) {
                if (ed[e] == j) {
                    a0 += x_s[es[e]][0];
                    a1 += x_s[es[e]][1];
                    a2 += x_s[es[e]][2];
                }
            }
            agg1[j][0] = a0; agg1[j][1] = a1; agg1[j][2] = a2;
        }
        __syncthreads();

        for (int n = 0; n < N_NODES; ++n) {
            float v = br1
                + agg1[n][0]*wr1_0 + agg1[n][1]*wr1_1 + agg1[n][2]*wr1_2
                + x_s[n][0]*wt1_0  + x_s[n][1]*wt1_1  + x_s[n][2]*wt1_2;
            h1[n][j]  = v;
            agg2[n][j] = 0.f;
        }
        __syncthreads();

        for (int e = 0; e < N_EDGES; ++e) {
            agg2[ed[e]][j] += h1[es[e]][j];
        }
        __syncthreads();

        float seqv = 0.f;
        for (int n = 0; n < N_NODES; ++n) {
            const float4* ag4 = (const float4*)agg2[n];
            const float4* h4  = (const float4*)h1[n];
            float acc0 = br2, acc1 = 0.f, acc2 = 0.f, acc3 = 0.f;
            #pragma unroll
            for (int k4 = 0; k4 < D_H/4; ++k4) {
                float4 av = ag4[k4];
                float4 hv = h4[k4];
                acc0 += av.x * wr2[4*k4+0] + hv.x * wt2[4*k4+0];
                acc1 += av.y * wr2[4*k4+1] + hv.y * wt2[4*k4+1];
                acc2 += av.z * wr2[4*k4+2] + hv.z * wt2[4*k4+2];
                acc3 += av.w * wr2[4*k4+3] + hv.w * wt2[4*k4+3];
            }
            float acc = (acc0 + acc1) + (acc2 + acc3);
            seqv += fmaxf(acc, 0.f);
        }
        seq_s[tt][j] = seqv * (1.0f / 33.0f);
    }
    __syncthreads();

    #pragma unroll
    for (int m = 0; m < 8; ++m) {
        const int o = m * 64 + j;
        const float bias = b_ih[o] + b_hh[o];
        const float4* w4 = (const float4*)(W_ih + (size_t)o * D_H);
        float acc[TB];
        #pragma unroll
        for (int tt = 0; tt < TB; ++tt) acc[tt] = bias;
        #pragma unroll
        for (int k4 = 0; k4 < D_H/4; ++k4) {
            float4 wv = w4[k4];
            #pragma unroll
            for (int tt = 0; tt < TB; ++tt) {
                const float4* s4 = (const float4*)seq_s[tt];
                float4 sv = s4[k4];
                acc[tt] += sv.x*wv.x + sv.y*wv.y + sv.z*wv.z + sv.w*wv.w;
            }
        }
        #pragma unroll
        for (int tt = 0; tt < TB; ++tt) {
            A[(size_t)(t0 + tt) * 512 + o] = acc[tt];
        }
    }
}

// ---------------------------------------------------------------------------
// Kernel 2: sequential LSTM, single block (1 CU), 256 threads = 4 waves,
// 1 wave/SIMD (amdgpu_waves_per_eu(1,1) -> 512-VGPR budget).
//
// Thread pair (2p, 2p+1) owns the FOUR gate rows of h_p:
//   even thread: rows p      (gate i) and 128+p (gate f)
//   odd  thread: rows 256+p  (gate g) and 384+p (gate o)
// Weights: 2 rows/thread = 64 NAMED float4 (256 VGPRs), asm-pinned so the
// compiler cannot sink/remat the loads into the loop (round-2 failure mode).
// Gate exchange within the pair via 2x __shfl_xor (no LDS round trip);
// nonlinearity computed redundantly by both pair threads (identical ops,
// deterministic). h double-buffered in LDS -> ONE barrier per step.
// ---------------------------------------------------------------------------
__device__ __forceinline__ float sigmoid_f(float v) {
    return 1.0f / (1.0f + __expf(-v));
}
__device__ __forceinline__ float tanh_f(float v) {
    return 1.0f - 2.0f / (1.0f + __expf(2.0f * v));
}

#define R32(M) M(0) M(1) M(2) M(3) M(4) M(5) M(6) M(7) \
               M(8) M(9) M(10) M(11) M(12) M(13) M(14) M(15) \
               M(16) M(17) M(18) M(19) M(20) M(21) M(22) M(23) \
               M(24) M(25) M(26) M(27) M(28) M(29) M(30) M(31)

__global__ __launch_bounds__(256, 1)
__attribute__((amdgpu_waves_per_eu(1, 1)))
void lstm_kernel(
    const float* __restrict__ A,      // (T,512)
    const float* __restrict__ W_hh,   // (512,128)
    const float* __restrict__ W_fc,   // (5,128)
    const float* __restrict__ b_fc,   // (5,)
    float* __restrict__ out)          // (5,)
{
    const int tid  = threadIdx.x;   // 0..255
    const int pj   = tid >> 1;      // h index 0..127
    const int half = tid & 1;       // 0: gates i,f   1: gates g,o
    const int ra   = half ? (256 + pj) : pj;
    const int rb   = half ? (384 + pj) : (128 + pj);

    __shared__ __align__(16) float h_s[2 * D_LSTM];   // double-buffered h

    const float4* Wa4 = (const float4*)(W_hh + (size_t)ra * D_LSTM);
    const float4* Wb4 = (const float4*)(W_hh + (size_t)rb * D_LSTM);

    // ---- 64 named float4 weight registers, loaded once, asm-pinned ----
#define DECLW(i) float4 wa##i = Wa4[i]; float4 wb##i = Wb4[i];
    R32(DECLW)
#undef DECLW
#define PINW(i) asm volatile("" : "+v"(wa##i.x), "+v"(wa##i.y), "+v"(wa##i.z), "+v"(wa##i.w), \
                                  "+v"(wb##i.x), "+v"(wb##i.y), "+v"(wb##i.z), "+v"(wb##i.w));
    R32(PINW)
#undef PINW

    float c = 0.f;
    if (tid < D_LSTM) h_s[tid] = 0.f;   // buffer 0 = h_{-1} = 0
    __syncthreads();

    // prefetch A[0]
    float ax = A[ra];
    float ay = A[rb];

    for (int t = 0; t < T_LEN; ++t) {
        const float ga_in = ax;
        const float gb_in = ay;
        const int tn = (t + 1) & (T_LEN - 1);          // branchless wrap
        ax = A[(size_t)tn * 512 + ra];                 // prefetch next step
        ay = A[(size_t)tn * 512 + rb];

        // ---- matvec: ga = ga_in + h·W[ra], gb = gb_in + h·W[rb] ----
        const float4* h4 = (const float4*)(h_s + (t & 1) * D_LSTM);
        float a0 = 0.f, a1 = 0.f, a2 = 0.f, a3 = 0.f;
        float b0 = 0.f, b1 = 0.f, b2 = 0.f, b3 = 0.f;
#define FMA_STEP(i) { float4 hv = h4[i]; \
        a0 = __builtin_fmaf(hv.x, wa##i.x, a0); a1 = __builtin_fmaf(hv.y, wa##i.y, a1); \
        a2 = __builtin_fmaf(hv.z, wa##i.z, a2); a3 = __builtin_fmaf(hv.w, wa##i.w, a3); \
        b0 = __builtin_fmaf(hv.x, wb##i.x, b0); b1 = __builtin_fmaf(hv.y, wb##i.y, b1); \
        b2 = __builtin_fmaf(hv.z, wb##i.z, b2); b3 = __builtin_fmaf(hv.w, wb##i.w, b3); }
        R32(FMA_STEP)
#undef FMA_STEP
        const float ga = ga_in + ((a0 + a1) + (a2 + a3));
        const float gb = gb_in + ((b0 + b1) + (b2 + b3));

        // ---- pair exchange: each thread ends with all 4 gates of h_pj ----
        const float pga = __shfl_xor(ga, 1);
        const float pgb = __shfl_xor(gb, 1);
        const float gi = half ? pga : ga;
        const float gf = half ? pgb : gb;
        const float gg = half ? ga : pga;
        const float go = half ? gb : pgb;

        // ---- nonlinearity (redundant in both pair threads, identical) ----
        const float si = sigmoid_f(gi);
        const float sf = sigmoid_f(gf);
        const float so = sigmoid_f(go);
        const float tg = tanh_f(gg);
        c = sf * c + si * tg;
        const float hv = so * tanh_f(c);

        h_s[((t + 1) & 1) * D_LSTM + pj] = hv;   // write other buffer
        __syncthreads();                          // ONE barrier per step
    }

    // final FC: out = hT @ W_fc.T + b_fc   (final h is in buffer 0)
    if (tid < N_CLS) {
        float acc = b_fc[tid];
        #pragma unroll
        for (int k = 0; k < D_LSTM; ++k) acc += h_s[k] * W_fc[tid * D_LSTM + k];
        out[tid] = acc;
    }
}

// ---------------------------------------------------------------------------
extern "C" void kernel_launch(void* const* d_in, const int* in_sizes, int n_in,
                              void* d_out, int out_size, void* d_ws, size_t ws_size,
                              hipStream_t stream) {
    const float* x       = (const float*)d_in[0];
    const int*   esrc    = (const int*)  d_in[1];
    const int*   edst    = (const int*)  d_in[2];
    const float* W_rel1  = (const float*)d_in[3];
    const float* b_rel1  = (const float*)d_in[4];
    const float* W_root1 = (const float*)d_in[5];
    const float* W_rel2  = (const float*)d_in[6];
    const float* b_rel2  = (const float*)d_in[7];
    const float* W_root2 = (const float*)d_in[8];
    const float* W_ih    = (const float*)d_in[9];
    const float* W_hh    = (const float*)d_in[10];
    const float* b_ih    = (const float*)d_in[11];
    const float* b_hh    = (const float*)d_in[12];
    const float* W_fc    = (const float*)d_in[13];
    const float* b_fc    = (const float*)d_in[14];

    float* out = (float*)d_out;
    float* A   = (float*)d_ws;   // (T,512) f32 = 16 MB

    gnn_proj_kernel<<<T_LEN / TB, 64, 0, stream>>>(
        x, esrc, edst, W_rel1, b_rel1, W_root1,
        W_rel2, b_rel2, W_root2, W_ih, b_ih, b_hh, A);

    lstm_kernel<<<1, 256, 0, stream>>>(A, W_hh, W_fc, b_fc, out);
}

// Round 4
// 8991.335 us; speedup vs baseline: 1.4408x; 1.0372x over previous
//
#include <hip/hip_runtime.h>

#define T_LEN 8192
#define N_NODES 33
#define N_EDGES 64
#define DIM_IN 3
#define D_H 64
#define D_LSTM 128
#define N_CLS 5
#define TB 4   // timesteps per block in kernel 1

// ---------------------------------------------------------------------------
// Kernel 1: graph conv x2 + relu + mean over nodes + input-side LSTM projection
// Writes A[t][o] = seq_t @ W_ih.T + b_ih + b_hh   (T x 512)
// ---------------------------------------------------------------------------
__global__ __launch_bounds__(64, 2) void gnn_proj_kernel(
    const float* __restrict__ x,        // (T,33,3)
    const int*   __restrict__ esrc,     // (64,)
    const int*   __restrict__ edst,     // (64,)
    const float* __restrict__ W_rel1,   // (64,3)
    const float* __restrict__ b_rel1,   // (64,)
    const float* __restrict__ W_root1,  // (64,3)
    const float* __restrict__ W_rel2,   // (64,64)
    const float* __restrict__ b_rel2,   // (64,)
    const float* __restrict__ W_root2,  // (64,64)
    const float* __restrict__ W_ih,     // (512,64)
    const float* __restrict__ b_ih,     // (512,)
    const float* __restrict__ b_hh,     // (512,)
    float* __restrict__ A)              // (T,512)  [workspace]
{
    const int t0 = blockIdx.x * TB;
    const int j  = threadIdx.x;   // 0..63

    __shared__ __align__(16) float x_s[N_NODES][DIM_IN];
    __shared__ __align__(16) float agg1[N_NODES][DIM_IN];
    __shared__ __align__(16) float h1[N_NODES][D_H];
    __shared__ __align__(16) float agg2[N_NODES][D_H];
    __shared__ __align__(16) float seq_s[TB][D_H];
    __shared__ int es[N_EDGES], ed[N_EDGES];

    es[j] = esrc[j];
    ed[j] = edst[j];

    const float wr1_0 = W_rel1[j*3+0], wr1_1 = W_rel1[j*3+1], wr1_2 = W_rel1[j*3+2];
    const float wt1_0 = W_root1[j*3+0], wt1_1 = W_root1[j*3+1], wt1_2 = W_root1[j*3+2];
    const float br1 = b_rel1[j];
    const float br2 = b_rel2[j];

    float wr2[D_H], wt2[D_H];
    #pragma unroll
    for (int k = 0; k < D_H; ++k) {
        wr2[k] = W_rel2[j*D_H + k];
        wt2[k] = W_root2[j*D_H + k];
    }

    for (int tt = 0; tt < TB; ++tt) {
        const int t = t0 + tt;
        __syncthreads();

        const float* xt = x + (size_t)t * (N_NODES * DIM_IN);
        for (int i = j; i < N_NODES * DIM_IN; i += 64) x_s[0][i] = xt[i];
        __syncthreads();

        if (j < N_NODES) {
            float a0 = 0.f, a1 = 0.f, a2 = 0.f;
            for (int e = 0; e < N_EDGES; ++e) {
                if (ed[e] == j) {
                    a0 += x_s[es[e]][0];
                    a1 += x_s[es[e]][1];
                    a2 += x_s[es[e]][2];
                }
            }
            agg1[j][0] = a0; agg1[j][1] = a1; agg1[j][2] = a2;
        }
        __syncthreads();

        for (int n = 0; n < N_NODES; ++n) {
            float v = br1
                + agg1[n][0]*wr1_0 + agg1[n][1]*wr1_1 + agg1[n][2]*wr1_2
                + x_s[n][0]*wt1_0  + x_s[n][1]*wt1_1  + x_s[n][2]*wt1_2;
            h1[n][j]  = v;
            agg2[n][j] = 0.f;
        }
        __syncthreads();

        for (int e = 0; e < N_EDGES; ++e) {
            agg2[ed[e]][j] += h1[es[e]][j];
        }
        __syncthreads();

        float seqv = 0.f;
        for (int n = 0; n < N_NODES; ++n) {
            const float4* ag4 = (const float4*)agg2[n];
            const float4* h4  = (const float4*)h1[n];
            float acc0 = br2, acc1 = 0.f, acc2 = 0.f, acc3 = 0.f;
            #pragma unroll
            for (int k4 = 0; k4 < D_H/4; ++k4) {
                float4 av = ag4[k4];
                float4 hv = h4[k4];
                acc0 += av.x * wr2[4*k4+0] + hv.x * wt2[4*k4+0];
                acc1 += av.y * wr2[4*k4+1] + hv.y * wt2[4*k4+1];
                acc2 += av.z * wr2[4*k4+2] + hv.z * wt2[4*k4+2];
                acc3 += av.w * wr2[4*k4+3] + hv.w * wt2[4*k4+3];
            }
            float acc = (acc0 + acc1) + (acc2 + acc3);
            seqv += fmaxf(acc, 0.f);
        }
        seq_s[tt][j] = seqv * (1.0f / 33.0f);
    }
    __syncthreads();

    #pragma unroll
    for (int m = 0; m < 8; ++m) {
        const int o = m * 64 + j;
        const float bias = b_ih[o] + b_hh[o];
        const float4* w4 = (const float4*)(W_ih + (size_t)o * D_H);
        float acc[TB];
        #pragma unroll
        for (int tt = 0; tt < TB; ++tt) acc[tt] = bias;
        #pragma unroll
        for (int k4 = 0; k4 < D_H/4; ++k4) {
            float4 wv = w4[k4];
            #pragma unroll
            for (int tt = 0; tt < TB; ++tt) {
                const float4* s4 = (const float4*)seq_s[tt];
                float4 sv = s4[k4];
                acc[tt] += sv.x*wv.x + sv.y*wv.y + sv.z*wv.z + sv.w*wv.w;
            }
        }
        #pragma unroll
        for (int tt = 0; tt < TB; ++tt) {
            A[(size_t)(t0 + tt) * 512 + o] = acc[tt];
        }
    }
}

// ---------------------------------------------------------------------------
// Kernel 2: sequential LSTM, single block (1 CU), 512 threads = 8 waves,
// 2 waves/SIMD (256-VGPR budget).
//
// 2D decomposition: lane = (idx<<2) | (kh<<1) | pairbit, q = wave*16 + idx.
//   pairbit=0 -> gate rows {q, 128+q}      (i_q, f_q)
//   pairbit=1 -> gate rows {256+q, 384+q}  (g_q, o_q)
//   kh        -> K-half [64*kh, 64*kh+64)
// Per thread: 2 rows x 64 K = 32 named float4 weights (128 VGPRs, asm-pinned,
// fits cleanly under the 256 budget -> no spill, the round-3 failure mode).
// K-half reduce = shfl_xor(2); gate pair exchange = shfl_xor(1); all 4 quad
// threads compute the identical nonlinearity (deterministic). h double-
// buffered in LDS, ONE barrier per step; 16 ds_read_b128 of h per thread.
// ---------------------------------------------------------------------------
__device__ __forceinline__ float sigmoid_f(float v) {
    return 1.0f / (1.0f + __expf(-v));
}
__device__ __forceinline__ float tanh_f(float v) {
    return 1.0f - 2.0f / (1.0f + __expf(2.0f * v));
}

#define R16(M) M(0) M(1) M(2) M(3) M(4) M(5) M(6) M(7) \
               M(8) M(9) M(10) M(11) M(12) M(13) M(14) M(15)

__global__ __launch_bounds__(512, 2)
__attribute__((amdgpu_waves_per_eu(2, 2)))
void lstm_kernel(
    const float* __restrict__ A,      // (T,512)
    const float* __restrict__ W_hh,   // (512,128)
    const float* __restrict__ W_fc,   // (5,128)
    const float* __restrict__ b_fc,   // (5,)
    float* __restrict__ out)          // (5,)
{
    const int tid     = threadIdx.x;        // 0..511
    const int lane    = tid & 63;
    const int wave    = tid >> 6;
    const int pairbit = lane & 1;
    const int kh      = (lane >> 1) & 1;
    const int idx     = lane >> 2;
    const int q       = wave * 16 + idx;    // h index 0..127
    const int ra      = pairbit ? (256 + q) : q;          // i or g row
    const int rb      = pairbit ? (384 + q) : (128 + q);  // f or o row
    const int kbase   = kh * 64;

    __shared__ __align__(16) float h_s[2 * D_LSTM];   // double-buffered h

    const float4* Wa4 = (const float4*)(W_hh + (size_t)ra * D_LSTM + kbase);
    const float4* Wb4 = (const float4*)(W_hh + (size_t)rb * D_LSTM + kbase);

    // ---- 32 named float4 weight registers (128 VGPRs), loaded once, pinned ----
#define DECLW(i) float4 wa##i = Wa4[i]; float4 wb##i = Wb4[i];
    R16(DECLW)
#undef DECLW
#define PINW(i) asm volatile("" : "+v"(wa##i.x), "+v"(wa##i.y), "+v"(wa##i.z), "+v"(wa##i.w), \
                                  "+v"(wb##i.x), "+v"(wb##i.y), "+v"(wb##i.z), "+v"(wb##i.w));
    R16(PINW)
#undef PINW

    float c = 0.f;
    if (tid < D_LSTM) h_s[tid] = 0.f;   // buffer 0 = h_{-1} = 0
    __syncthreads();

    // prefetch A[0] rows
    float ax = A[ra];
    float ay = A[rb];

    for (int t = 0; t < T_LEN; ++t) {
        const float a_ra = ax;
        const float a_rb = ay;
        const int tn = (t + 1) & (T_LEN - 1);          // branchless wrap
        ax = A[(size_t)tn * 512 + ra];                 // prefetch next step
        ay = A[(size_t)tn * 512 + rb];

        // ---- partial matvec over this thread's K-half ----
        const float4* h4 = (const float4*)(h_s + (t & 1) * D_LSTM + kbase);
        float a0 = 0.f, a1 = 0.f, a2 = 0.f, a3 = 0.f;
        float b0 = 0.f, b1 = 0.f, b2 = 0.f, b3 = 0.f;
#define FMA_STEP(i) { float4 hv = h4[i]; \
        a0 = __builtin_fmaf(hv.x, wa##i.x, a0); a1 = __builtin_fmaf(hv.y, wa##i.y, a1); \
        a2 = __builtin_fmaf(hv.z, wa##i.z, a2); a3 = __builtin_fmaf(hv.w, wa##i.w, a3); \
        b0 = __builtin_fmaf(hv.x, wb##i.x, b0); b1 = __builtin_fmaf(hv.y, wb##i.y, b1); \
        b2 = __builtin_fmaf(hv.z, wb##i.z, b2); b3 = __builtin_fmaf(hv.w, wb##i.w, b3); }
        R16(FMA_STEP)
#undef FMA_STEP
        const float pa = (a0 + a1) + (a2 + a3);
        const float pb = (b0 + b1) + (b2 + b3);

        // ---- K-half reduction (lane^2 = other kh, same rows) ----
        const float ga = a_ra + (pa + __shfl_xor(pa, 2));
        const float gb = a_rb + (pb + __shfl_xor(pb, 2));

        // ---- pair exchange (lane^1 = other gate pair of same q) ----
        const float pga = __shfl_xor(ga, 1);
        const float pgb = __shfl_xor(gb, 1);
        const float gi = pairbit ? pga : ga;
        const float gf = pairbit ? pgb : gb;
        const float gg = pairbit ? ga : pga;
        const float go = pairbit ? gb : pgb;

        // ---- nonlinearity (identical in all 4 quad threads, deterministic) ----
        const float si = sigmoid_f(gi);
        const float sf = sigmoid_f(gf);
        const float so = sigmoid_f(go);
        const float tg = tanh_f(gg);
        c = sf * c + si * tg;
        const float hv = so * tanh_f(c);

        if ((lane & 3) == 0) h_s[((t + 1) & 1) * D_LSTM + q] = hv;
        __syncthreads();                          // ONE barrier per step
    }

    // final FC: out = hT @ W_fc.T + b_fc   (final h is in buffer 0)
    if (tid < N_CLS) {
        float acc = b_fc[tid];
        #pragma unroll
        for (int k = 0; k < D_LSTM; ++k) acc += h_s[k] * W_fc[tid * D_LSTM + k];
        out[tid] = acc;
    }
}

// ---------------------------------------------------------------------------
extern "C" void kernel_launch(void* const* d_in, const int* in_sizes, int n_in,
                              void* d_out, int out_size, void* d_ws, size_t ws_size,
                              hipStream_t stream) {
    const float* x       = (const float*)d_in[0];
    const int*   esrc    = (const int*)  d_in[1];
    const int*   edst    = (const int*)  d_in[2];
    const float* W_rel1  = (const float*)d_in[3];
    const float* b_rel1  = (const float*)d_in[4];
    const float* W_root1 = (const float*)d_in[5];
    const float* W_rel2  = (const float*)d_in[6];
    const float* b_rel2  = (const float*)d_in[7];
    const float* W_root2 = (const float*)d_in[8];
    const float* W_ih    = (const float*)d_in[9];
    const float* W_hh    = (const float*)d_in[10];
    const float* b_ih    = (const float*)d_in[11];
    const float* b_hh    = (const float*)d_in[12];
    const float* W_fc    = (const float*)d_in[13];
    const float* b_fc    = (const float*)d_in[14];

    float* out = (float*)d_out;
    float* A   = (float*)d_ws;   // (T,512) f32 = 16 MB

    gnn_proj_kernel<<<T_LEN / TB, 64, 0, stream>>>(
        x, esrc, edst, W_rel1, b_rel1, W_root1,
        W_rel2, b_rel2, W_root2, W_ih, b_ih, b_hh, A);

    lstm_kernel<<<1, 512, 0, stream>>>(A, W_hh, W_fc, b_fc, out);
}